// Round 4
// baseline (125056.140 us; speedup 1.0000x reference)
//
#include <hip/hip_runtime.h>
#include <cstdint>
#include <cstring>
#include <vector>

// Flip to 0 if round shows globally-wrong outputs (legacy JAX threefry derivation).
#define RNG_PARTITIONABLE 1

#define NS 131072
#define D  128
#define KC 512
#define CAPC 256
#define TS 32

// ---------------- workspace layout (bytes) ----------------
static constexpr size_t OFF_YT    = 0;                                   // double[128*512]
static constexpr size_t OFF_Y2    = OFF_YT + (size_t)D * KC * 8;         // double[512]
static constexpr size_t OFF_CB    = OFF_Y2 + (size_t)KC * 8;             // float[512*128]
static constexpr size_t OFF_NORM  = OFF_CB + (size_t)KC * D * 4;         // double
static constexpr size_t OFF_DONE  = OFF_NORM + 8;                        // u32
static constexpr size_t OFF_SCAL  = OFF_DONE + 4;                        // u32[3]: pos, open, olc
static constexpr size_t OFF_CNT   = OFF_SCAL + 12;                       // u32[512]
static constexpr size_t OFF_OPENL = OFF_CNT + (size_t)KC * 4;            // u16[512]
static constexpr size_t OFF_MCNT  = OFF_OPENL + (size_t)KC * 2;          // u32[512]
static constexpr size_t OFF_MEMB  = OFF_MCNT + (size_t)KC * 4;           // u32[512*256]
static constexpr size_t OFF_LBL   = OFF_MEMB + (size_t)KC * CAPC * 4;    // int32[NS]
static constexpr size_t OFF_SL    = ((OFF_LBL + (size_t)NS * 4 + 15) / 16) * 16; // u16[NS*32]

struct PermArg { uint32_t v[KC]; };

// ---------------- device helpers ----------------
__device__ inline unsigned long long sortkey(double d) {
  unsigned long long u = (unsigned long long)__double_as_longlong(d);
  return (u & 0x8000000000000000ull) ? ~u : (u | 0x8000000000000000ull);
}

__device__ inline double dot128(const float* __restrict__ x, const float* __restrict__ y) {
  double s0 = 0, s1 = 0, s2 = 0, s3 = 0;
#pragma unroll
  for (int k = 0; k < D; k += 4) {
    float4 a = *reinterpret_cast<const float4*>(x + k);
    float4 b = *reinterpret_cast<const float4*>(y + k);
    s0 = fma((double)a.x, (double)b.x, s0);
    s1 = fma((double)a.y, (double)b.y, s1);
    s2 = fma((double)a.z, (double)b.z, s2);
    s3 = fma((double)a.w, (double)b.w, s3);
  }
  return (s0 + s1) + (s2 + s3);
}

__device__ inline void bitonic64(unsigned long long& k, uint32_t& v, int lane) {
#pragma unroll
  for (int sz = 2; sz <= 64; sz <<= 1) {
#pragma unroll
    for (int st = sz >> 1; st > 0; st >>= 1) {
      unsigned long long ok = __shfl_xor(k, st);
      uint32_t ov = __shfl_xor(v, st);
      bool dirAsc = ((lane & sz) == 0);
      bool low = ((lane & st) == 0);
      bool oless = (ok < k) || (ok == k && ov < v);
      bool take = (dirAsc == low) ? oless : !oless;
      if (take) { k = ok; v = ov; }
    }
  }
}

// ---------------- init kernels ----------------
__global__ void k_init(uint32_t* done) {
  if (threadIdx.x == 0 && blockIdx.x == 0) *done = 0u;
}

__global__ void k_gather(PermArg p, const float* __restrict__ data, float* __restrict__ cb) {
  int c = blockIdx.x, t = threadIdx.x;
  cb[(size_t)c * D + t] = data[(size_t)p.v[c] * D + t];
}

// per-iteration prep: y2 (f64) and transposed f64 codebook
__global__ __launch_bounds__(64) void k_prep(const float* __restrict__ cb,
    double* __restrict__ yT, double* __restrict__ y2g, const uint32_t* __restrict__ done) {
  if (*done) return;
  const int c = blockIdx.x;
  const int lane = threadIdx.x;
  double v0 = (double)cb[(size_t)c * D + lane];
  double v1 = (double)cb[(size_t)c * D + 64 + lane];
  yT[(size_t)lane * KC + c] = v0;
  yT[(size_t)(lane + 64) * KC + c] = v1;
  double q = fma(v0, v0, v1 * v1);
  for (int d2 = 32; d2; d2 >>= 1) q += __shfl_xor(q, d2);
  if (lane == 0) y2g[c] = q;
}

// ---------------- fused f64 distance + exact top-32 shortlist ----------------
// block = 256 threads handles 16 rows; thread owns clusters (tid, tid+256) for all 16 rows.
__global__ __launch_bounds__(256) void k_dist(const float* __restrict__ data,
    const double* __restrict__ yT, const double* __restrict__ y2g,
    uint16_t* __restrict__ sl, const uint32_t* __restrict__ done) {
  if (*done) return;
  __shared__ double xs[16][D];
  __shared__ uint32_t hist[256];
  __shared__ unsigned long long candK[64];
  __shared__ uint32_t candI[64];
  __shared__ uint32_t candCnt;
  __shared__ double redMn[4], redMx[4];
  __shared__ double sKey[4];
  __shared__ int sId[4];
  __shared__ int cutSh;
  __shared__ uint32_t totSh;
  __shared__ int winSh;

  const int tid = threadIdx.x;
  const int lane = tid & 63;
  const int wv = tid >> 6;
  const int rowBase = blockIdx.x * 16;

  for (int idx = tid; idx < 16 * D; idx += 256) {
    int r = idx >> 7, k = idx & 127;
    xs[r][k] = (double)data[(size_t)(rowBase + r) * D + k];
  }
  __syncthreads();

  const int c0 = tid, c1 = tid + 256;
  double acc0[16], acc1[16];
#pragma unroll
  for (int r = 0; r < 16; ++r) { acc0[r] = 0.0; acc1[r] = 0.0; }

  for (int k = 0; k < D; ++k) {
    double yv0 = yT[(size_t)k * KC + c0];
    double yv1 = yT[(size_t)k * KC + c1];
#pragma unroll
    for (int r = 0; r < 16; ++r) {
      double xv = xs[r][k];
      acc0[r] = fma(xv, yv0, acc0[r]);
      acc1[r] = fma(xv, yv1, acc1[r]);
    }
  }
  {
    double y20 = y2g[c0], y21 = y2g[c1];
#pragma unroll
    for (int r = 0; r < 16; ++r) {
      acc0[r] = fma(-2.0, acc0[r], y20);   // S = y2 - 2 x.y
      acc1[r] = fma(-2.0, acc1[r], y21);
    }
  }

#pragma unroll
  for (int r = 0; r < 16; ++r) {
    const double v0 = acc0[r], v1 = acc1[r];
    // block min/max
    double mn = fmin(v0, v1), mx = fmax(v0, v1);
    for (int d2 = 32; d2; d2 >>= 1) {
      mn = fmin(mn, __shfl_xor(mn, d2));
      mx = fmax(mx, __shfl_xor(mx, d2));
    }
    if (lane == 0) { redMn[wv] = mn; redMx[wv] = mx; }
    __syncthreads();
    mn = fmin(fmin(redMn[0], redMn[1]), fmin(redMn[2], redMn[3]));
    mx = fmax(fmax(redMx[0], redMx[1]), fmax(redMx[2], redMx[3]));
    double rng = mx - mn;
    double inv = (rng > 0.0) ? (255.0 / rng) : 0.0;
    hist[tid] = 0;
    if (tid == 0) candCnt = 0;
    __syncthreads();
    int b0 = (int)((v0 - mn) * inv); b0 = b0 < 0 ? 0 : (b0 > 255 ? 255 : b0);
    int b1 = (int)((v1 - mn) * inv); b1 = b1 < 0 ? 0 : (b1 > 255 ? 255 : b1);
    atomicAdd(&hist[b0], 1u);
    atomicAdd(&hist[b1], 1u);
    __syncthreads();
    if (wv == 0) {
      uint32_t h0 = hist[lane * 4], h1 = hist[lane * 4 + 1], h2 = hist[lane * 4 + 2], h3 = hist[lane * 4 + 3];
      uint32_t ls = h0 + h1 + h2 + h3, x = ls;
      for (int d2 = 1; d2 < 64; d2 <<= 1) { uint32_t y = __shfl_up(x, d2); if (lane >= d2) x += y; }
      uint32_t e = x - ls;
      uint32_t cA = e + h0, cB = cA + h1, cC = cB + h2, cD = cC + h3;
      int mc = 999; uint32_t mt = 0;
      if (cA >= 32) { mc = lane * 4; mt = cA; }
      else if (cB >= 32) { mc = lane * 4 + 1; mt = cB; }
      else if (cC >= 32) { mc = lane * 4 + 2; mt = cC; }
      else if (cD >= 32) { mc = lane * 4 + 3; mt = cD; }
      for (int d2 = 32; d2; d2 >>= 1) {
        int oc = __shfl_xor(mc, d2); uint32_t ot = __shfl_xor(mt, d2);
        if (oc < mc) { mc = oc; mt = ot; }
      }
      if (lane == 0) { cutSh = mc; totSh = mt; }
    }
    __syncthreads();
    const int cut = cutSh;
    const uint32_t tot = totSh;
    if (tot <= 64u) {
      if (b0 <= cut) { uint32_t s2 = atomicAdd(&candCnt, 1u); candK[s2] = sortkey(v0); candI[s2] = (uint32_t)c0; }
      if (b1 <= cut) { uint32_t s2 = atomicAdd(&candCnt, 1u); candK[s2] = sortkey(v1); candI[s2] = (uint32_t)c1; }
      __syncthreads();
      if (wv == 0) {
        uint32_t nc = candCnt;
        unsigned long long kk = ~0ull; uint32_t id = 0xFFFFu;
        if ((uint32_t)lane < nc) { kk = candK[lane]; id = candI[lane]; }
        bitonic64(kk, id, lane);
        if (lane < TS) sl[(size_t)(rowBase + r) * TS + lane] = (uint16_t)id;
      }
      __syncthreads();
    } else {
      // exact slow path (rare): 32 rounds of block-wide argmin
      uint32_t tk = 0;
      for (int sel = 0; sel < 32; ++sel) {
        double bv = 1e300; int bc = 0x7FFFFFFF;
        if (!(tk & 1u)) { bv = v0; bc = c0; }
        if (!(tk & 2u) && (v1 < bv || (v1 == bv && c1 < bc))) { bv = v1; bc = c1; }
        for (int d2 = 32; d2; d2 >>= 1) {
          double ov = __shfl_xor(bv, d2); int oc = __shfl_xor(bc, d2);
          if (ov < bv || (ov == bv && oc < bc)) { bv = ov; bc = oc; }
        }
        if (lane == 0) { sKey[wv] = bv; sId[wv] = bc; }
        __syncthreads();
        if (tid == 0) {
          double fb = sKey[0]; int fc = sId[0];
          for (int w2 = 1; w2 < 4; ++w2) {
            if (sKey[w2] < fb || (sKey[w2] == fb && sId[w2] < fc)) { fb = sKey[w2]; fc = sId[w2]; }
          }
          winSh = fc;
          sl[(size_t)(rowBase + r) * TS + sel] = (uint16_t)fc;
        }
        __syncthreads();
        int wc = winSh;
        if (tid == (wc & 255)) tk |= (wc < 256) ? 1u : 2u;
        __syncthreads();
      }
    }
  }
}

// ---------------- sequential greedy (exact), single-wave event loop ----------------
__device__ inline int walkstep(const uint4 cc, const uint16_t* __restrict__ sl,
    uint32_t i, int& ptr, const uint32_t* cnt) {
  while (ptr < TS) {
    uint32_t c;
    if (ptr < 8) {
      uint32_t w = (ptr < 4) ? ((ptr < 2) ? cc.x : cc.y) : ((ptr < 6) ? cc.z : cc.w);
      c = (w >> ((ptr & 1) * 16)) & 0xFFFFu;
    } else {
      c = sl[(size_t)i * TS + ptr];
    }
    if (c < KC && cnt[c] < CAPC) return (int)c;
    ++ptr;
  }
  return -1;
}

__device__ inline void resolve_overflow(int& choice, uint32_t i, int lane,
    const uint32_t* cnt, const double* __restrict__ y2g,
    const float* __restrict__ cb, const float* __restrict__ data) {
  unsigned long long om = __ballot(choice < 0);
  while (om) {
    int L = __ffsll(om) - 1;
    om &= om - 1;
    uint32_t iL = __shfl(i, L);
    const float* x = data + (size_t)iL * D;
    double bv = 1e300; int bc = 0x7FFFFFFF;
    for (int j = 0; j < 8; ++j) {
      int c = lane + 64 * j;
      if (cnt[c] < CAPC) {
        double v = y2g[c] - 2.0 * dot128(x, cb + (size_t)c * D);
        if (v < bv || (v == bv && c < bc)) { bv = v; bc = c; }
      }
    }
    for (int d2 = 32; d2; d2 >>= 1) {
      double ov = __shfl_xor(bv, d2); int oc = __shfl_xor(bc, d2);
      if (ov < bv || (ov == bv && oc < bc)) { bv = ov; bc = oc; }
    }
    if (lane == L) choice = bc;
  }
}

__global__ __launch_bounds__(64) void k_ev(const float* __restrict__ data,
    const float* __restrict__ cb, const double* __restrict__ y2g,
    const uint16_t* __restrict__ sl, uint32_t* __restrict__ cntG,
    uint32_t* __restrict__ scal, uint16_t* __restrict__ openLG,
    int* __restrict__ labels, const uint32_t* __restrict__ done,
    int stopOpen, int initFlag) {
  if (*done) return;
  __shared__ uint32_t cnt[KC];
  __shared__ uint32_t hist[KC];
  __shared__ uint32_t reach[96];
  __shared__ uint32_t reachCnt;
  __shared__ uint32_t openSh;
  __shared__ uint32_t posSh;
  __shared__ uint32_t olc;
  const int lane = threadIdx.x;

  if (initFlag) {
    for (int c = lane; c < KC; c += 64) cnt[c] = 0;
    if (lane == 0) { openSh = KC; posSh = 0; }
  } else {
    for (int c = lane; c < KC; c += 64) cnt[c] = cntG[c];
    if (lane == 0) { posSh = scal[0]; openSh = scal[1]; }
  }
  __syncthreads();
  uint32_t pos = posSh;

  uint4 pf0, pf1;
  {
    uint32_t s0 = pos + lane; if (s0 >= NS) s0 = NS - 1;
    uint32_t s1 = pos + 64 + lane; if (s1 >= NS) s1 = NS - 1;
    pf0 = *reinterpret_cast<const uint4*>(sl + (size_t)s0 * TS);
    pf1 = *reinterpret_cast<const uint4*>(sl + (size_t)s1 * TS);
  }

  while (pos < NS) {
    if (openSh <= (uint32_t)stopOpen) break;
    uint32_t i = pos + lane;
    uint4 pf2;
    {
      uint32_t s2i = pos + 128 + lane; if (s2i >= NS) s2i = NS - 1;
      pf2 = *reinterpret_cast<const uint4*>(sl + (size_t)s2i * TS);
    }
    int ptr = 0;
    bool exempt = false;
    int choice = walkstep(pf0, sl, i, ptr, cnt);
    resolve_overflow(choice, i, lane, cnt, y2g, cb, data);

    for (;;) {
      for (int c = lane; c < KC; c += 64) hist[c] = 0;
      if (lane == 0) reachCnt = 0;
      __syncthreads();
      if (!exempt) atomicAdd(&hist[choice], 1u);
      __syncthreads();
      for (int c = lane; c < KC; c += 64) {
        uint32_t cc = cnt[c];
        if (cc < CAPC && cc + hist[c] >= CAPC) {
          uint32_t s2 = atomicAdd(&reachCnt, 1u);
          if (s2 < 96) reach[s2] = c;
        }
      }
      __syncthreads();
      uint32_t nr = reachCnt; if (nr > 96) nr = 96;
      if (nr == 0) break;
      // pass 1: earliest invalid lane L*
      int Lstar = 64;
      for (uint32_t t = 0; t < nr; ++t) {
        uint32_t c = reach[t];
        uint32_t rem = CAPC - cnt[c];
        unsigned long long m = __ballot((!exempt) && choice == (int)c);
        if ((uint32_t)__popcll(m) > rem) {
          unsigned long long mm = m;
          for (uint32_t q = 0; q < rem; ++q) mm &= mm - 1;
          int fi = __ffsll(mm) - 1;
          if (fi < Lstar) Lstar = fi;
        }
      }
      if (Lstar == 64) break;  // only exact fills; commit via atomics
      // pass 2: fill every cluster whose fill lane precedes L*
      bool inval = false;
      for (uint32_t t = 0; t < nr; ++t) {
        uint32_t c = reach[t];
        uint32_t cc = cnt[c];
        if (cc >= CAPC) continue;
        uint32_t rem = CAPC - cc;
        unsigned long long m = __ballot((!exempt) && choice == (int)c);
        uint32_t pc = (uint32_t)__popcll(m);
        if (pc >= rem) {
          unsigned long long mm = m;
          for (uint32_t q = 0; q + 1 < rem; ++q) mm &= mm - 1;
          int fl = __ffsll(mm) - 1;
          if (fl < Lstar) {
            __syncthreads();
            if (lane == 0) { cnt[c] = CAPC; openSh--; }
            __syncthreads();
            if ((!exempt) && choice == (int)c) {
              uint32_t rk = (uint32_t)__popcll(m & ((1ull << lane) - 1ull));
              if (rk < rem) exempt = true; else inval = true;
            }
          }
        }
      }
      __syncthreads();
      if (inval) {
        if (ptr < TS) { ++ptr; choice = walkstep(pf0, sl, i, ptr, cnt); }
        else choice = -1;
      }
      resolve_overflow(choice, i, lane, cnt, y2g, cb, data);
      __syncthreads();
    }
    // commit
    uint32_t old = 0;
    if (!exempt) old = atomicAdd(&cnt[choice], 1u);
    labels[i] = choice;
    __syncthreads();
    if (!exempt && old == CAPC - 1) atomicSub(&openSh, 1u);
    __syncthreads();
    pos += 64;
    pf0 = pf1; pf1 = pf2;
  }

  __syncthreads();
  for (int c = lane; c < KC; c += 64) cntG[c] = cnt[c];
  if (lane == 0) olc = 0;
  __syncthreads();
  for (int j = 0; j < 8; ++j) {
    int c = lane + 64 * j;
    bool op = cnt[c] < CAPC;
    unsigned long long m = __ballot(op);
    uint32_t base = olc;
    uint32_t rk = (uint32_t)__popcll(m & ((1ull << lane) - 1ull));
    if (op) openLG[base + rk] = (uint16_t)c;
    __syncthreads();
    if (lane == 0) olc += (uint32_t)__popcll(m);
    __syncthreads();
  }
  if (lane == 0) { scal[0] = pos; scal[1] = openSh; scal[2] = olc; }
}

// rebuild shortlists for remaining samples over the (<=64) open clusters
__global__ __launch_bounds__(256) void k_rebuild(const float* __restrict__ data,
    const float* __restrict__ cb, const double* __restrict__ y2g,
    uint16_t* __restrict__ sl, const uint32_t* __restrict__ scal,
    const uint16_t* __restrict__ openLG, const uint32_t* __restrict__ done) {
  if (*done) return;
  uint32_t pos = scal[0];
  if (pos >= NS) return;
  uint32_t oc = scal[2]; if (oc > 64) oc = 64;
  const int lane = threadIdx.x & 63;
  const uint32_t wid = (blockIdx.x * blockDim.x + threadIdx.x) >> 6;
  const uint32_t nw = (gridDim.x * blockDim.x) >> 6;
  int c = -1; double y2v = 0.0; const float* yrow = cb;
  if ((uint32_t)lane < oc) { c = openLG[lane]; y2v = y2g[c]; yrow = cb + (size_t)c * D; }
  for (uint32_t s = pos + wid; s < NS; s += nw) {
    unsigned long long kk = ~0ull; uint32_t id = 0xFFFFu;
    if (c >= 0) {
      double v = y2v - 2.0 * dot128(data + (size_t)s * D, yrow);
      kk = sortkey(v); id = (uint32_t)c;
    }
    bitonic64(kk, id, lane);
    if (lane < TS) sl[(size_t)s * TS + lane] = (uint16_t)id;
  }
}

// ---------------- codebook update ----------------
__global__ void k_zero(uint32_t* mcnt, double* norm) {
  int i = blockIdx.x * blockDim.x + threadIdx.x;
  if (i < KC) mcnt[i] = 0u;
  if (i == 0) *norm = 0.0;
}

__global__ void k_scatter(const int* __restrict__ labels, uint32_t* __restrict__ mcnt,
    uint32_t* __restrict__ memb, const uint32_t* __restrict__ done) {
  if (*done) return;
  uint32_t i = blockIdx.x * blockDim.x + threadIdx.x;
  int c = labels[i];
  if ((unsigned)c < KC) {
    uint32_t s = atomicAdd(&mcnt[c], 1u);
    if (s < CAPC) memb[(size_t)c * CAPC + s] = i;
  }
}

__global__ __launch_bounds__(128) void k_update(const float* __restrict__ data,
    const uint32_t* __restrict__ memb, float* __restrict__ cb,
    double* __restrict__ norm, const uint32_t* __restrict__ done) {
  if (*done) return;
  const int c = blockIdx.x, t = threadIdx.x;
  __shared__ uint32_t mem[CAPC];
  __shared__ double qq[2];
  mem[t] = memb[(size_t)c * CAPC + t] & (NS - 1);
  mem[t + 128] = memb[(size_t)c * CAPC + 128 + t] & (NS - 1);
  __syncthreads();
  double a = 0.0;
  for (int m = 0; m < CAPC; ++m) a += (double)data[(size_t)mem[m] * D + t];
  float nv = (float)(a * (1.0 / 256.0));
  double df = (double)nv - (double)cb[(size_t)c * D + t];
  cb[(size_t)c * D + t] = nv;
  double q = df * df;
  for (int d2 = 32; d2; d2 >>= 1) q += __shfl_xor(q, d2);
  if ((t & 63) == 0) qq[t >> 6] = q;
  __syncthreads();
  if (t == 0) atomicAdd(norm, qq[0] + qq[1]);
}

__global__ void k_conv(const double* __restrict__ norm, uint32_t* __restrict__ done) {
  if (threadIdx.x == 0 && blockIdx.x == 0) {
    if (*norm < 1e-8) *done = 1u;   // norm < 1e-4  <=>  norm^2 < 1e-8
  }
}

__global__ void k_out(const float* __restrict__ cb, float* __restrict__ o) {
  int i = blockIdx.x * blockDim.x + threadIdx.x;
  o[i] = cb[i];
}

// labels are int32 internally; harness reads the whole d_out as float32 -> emit float values
__global__ void k_outL(const int* __restrict__ lbl, float* __restrict__ o) {
  int i = blockIdx.x * blockDim.x + threadIdx.x;
  o[i] = (float)lbl[i];
}

// ---------------- host: JAX threefry permutation (input-independent) ----------------
static void tf2x32(uint32_t k0, uint32_t k1, uint32_t x0, uint32_t x1, uint32_t& o0, uint32_t& o1) {
  uint32_t ks2 = k0 ^ k1 ^ 0x1BD11BDAu;
  x0 += k0; x1 += k1;
  auto R = [&](int r) { x0 += x1; x1 = (x1 << r) | (x1 >> (32 - r)); x1 ^= x0; };
  R(13); R(15); R(26); R(6);   x0 += k1;  x1 += ks2 + 1u;
  R(17); R(29); R(16); R(24);  x0 += ks2; x1 += k0 + 2u;
  R(13); R(15); R(26); R(6);   x0 += k0;  x1 += k1 + 3u;
  R(17); R(29); R(16); R(24);  x0 += k1;  x1 += ks2 + 4u;
  R(13); R(15); R(26); R(6);   x0 += ks2; x1 += k0 + 5u;
  o0 = x0; o1 = x1;
}

static void host_sort_kv(std::vector<uint32_t>& k, std::vector<uint32_t>& v) {
  const size_t n = k.size();
  std::vector<uint32_t> k2(n), v2(n);
  for (int sh = 0; sh < 32; sh += 8) {
    uint32_t cnt2[257];
    memset(cnt2, 0, sizeof cnt2);
    for (size_t i = 0; i < n; ++i) cnt2[((k[i] >> sh) & 255u) + 1]++;
    for (int b = 0; b < 256; ++b) cnt2[b + 1] += cnt2[b];
    for (size_t i = 0; i < n; ++i) {
      uint32_t b = (k[i] >> sh) & 255u;
      uint32_t d = cnt2[b]++;
      k2[d] = k[i]; v2[d] = v[i];
    }
    k.swap(k2); v.swap(v2);
  }
}

static void compute_perm(uint32_t* out) {
  const uint32_t n = NS;
  std::vector<uint32_t> vals(n), keys(n);
  for (uint32_t i = 0; i < n; ++i) vals[i] = i;
  uint32_t k0 = 0u, k1 = 42u;  // jax.random.key(42) -> [0, 42]
  for (int round = 0; round < 2; ++round) {   // num_rounds = ceil(3*ln(131072)/ln(2^32-1)) = 2
    uint32_t nk0, nk1, sk0, sk1;
#if RNG_PARTITIONABLE
    tf2x32(k0, k1, 0u, 0u, nk0, nk1);  // split-foldlike: keys[i] = TF(key,(0,i))
    tf2x32(k0, k1, 0u, 1u, sk0, sk1);
    for (uint32_t i = 0; i < n; ++i) {
      uint32_t b1, b2;
      tf2x32(sk0, sk1, 0u, i, b1, b2);
      keys[i] = b1 ^ b2;                // 32-bit bits = bits1 ^ bits2
    }
#else
    {
      uint32_t a0, b0, a1, b1v;
      tf2x32(k0, k1, 0u, 2u, a0, b0);  // original split: counts iota(4), pairs (0,2),(1,3)
      tf2x32(k0, k1, 1u, 3u, a1, b1v);
      nk0 = a0; nk1 = a1; sk0 = b0; sk1 = b1v;
    }
    {
      const uint32_t h = n / 2;
      for (uint32_t i = 0; i < h; ++i) {
        uint32_t o0, o1;
        tf2x32(sk0, sk1, i, i + h, o0, o1);
        keys[i] = o0; keys[i + h] = o1;
      }
    }
#endif
    host_sort_kv(keys, vals);  // stable ascending == lax.sort_key_val
    k0 = nk0; k1 = nk1;
  }
  memcpy(out, vals.data(), KC * sizeof(uint32_t));
}

// ---------------- launcher ----------------
extern "C" void kernel_launch(void* const* d_in, const int* in_sizes, int n_in,
                              void* d_out, int out_size, void* d_ws, size_t ws_size,
                              hipStream_t stream) {
  const float* data = (const float*)d_in[0];
  float* outCB = (float*)d_out;
  float* outLB = (float*)d_out + (size_t)KC * D;

  char* w = (char*)d_ws;
  double* yT = (double*)(w + OFF_YT);
  double* y2 = (double*)(w + OFF_Y2);
  float* cb = (float*)(w + OFF_CB);
  double* norm = (double*)(w + OFF_NORM);
  uint32_t* done = (uint32_t*)(w + OFF_DONE);
  uint32_t* scal = (uint32_t*)(w + OFF_SCAL);
  uint32_t* cnt = (uint32_t*)(w + OFF_CNT);
  uint16_t* openL = (uint16_t*)(w + OFF_OPENL);
  uint32_t* mcnt = (uint32_t*)(w + OFF_MCNT);
  uint32_t* memb = (uint32_t*)(w + OFF_MEMB);
  int* lbl = (int*)(w + OFF_LBL);
  uint16_t* sl = (uint16_t*)(w + OFF_SL);

  PermArg pa;
  compute_perm(pa.v);  // deterministic host work each call (capture-time only)

  k_init<<<1, 64, 0, stream>>>(done);
  k_gather<<<KC, D, 0, stream>>>(pa, data, cb);

  for (int it = 0; it < 3; ++it) {
    k_prep<<<KC, 64, 0, stream>>>(cb, yT, y2, done);
    k_dist<<<NS / 16, 256, 0, stream>>>(data, yT, y2, sl, done);
    k_ev<<<1, 64, 0, stream>>>(data, cb, y2, sl, cnt, scal, openL, lbl, done, 64, 1);
    k_rebuild<<<256, 256, 0, stream>>>(data, cb, y2, sl, scal, openL, done);
    k_ev<<<1, 64, 0, stream>>>(data, cb, y2, sl, cnt, scal, openL, lbl, done, 32, 0);
    k_rebuild<<<256, 256, 0, stream>>>(data, cb, y2, sl, scal, openL, done);
    k_ev<<<1, 64, 0, stream>>>(data, cb, y2, sl, cnt, scal, openL, lbl, done, 0, 0);
    k_zero<<<2, 256, 0, stream>>>(mcnt, norm);
    k_scatter<<<NS / 256, 256, 0, stream>>>(lbl, mcnt, memb, done);
    k_update<<<KC, 128, 0, stream>>>(data, memb, cb, norm, done);
    k_conv<<<1, 64, 0, stream>>>(norm, done);
  }
  k_out<<<KC * D / 256, 256, 0, stream>>>(cb, outCB);
  k_outL<<<NS / 256, 256, 0, stream>>>(lbl, outLB);
}

// Round 6
// 121445.312 us; speedup vs baseline: 1.0297x; 1.0297x over previous
//
#include <hip/hip_runtime.h>
#include <cstdint>
#include <cstring>
#include <vector>

// Flip to 0 if round shows globally-wrong outputs (legacy JAX threefry derivation).
#define RNG_PARTITIONABLE 1

#define NS 131072
#define D  128
#define KC 512
#define CAPC 256
#define TS 32

// ---------------- workspace layout (bytes) ----------------
static constexpr size_t OFF_YT    = 0;                                   // double[128*512]
static constexpr size_t OFF_Y2    = OFF_YT + (size_t)D * KC * 8;         // double[512]
static constexpr size_t OFF_CB    = OFF_Y2 + (size_t)KC * 8;             // float[512*128]
static constexpr size_t OFF_NORM  = OFF_CB + (size_t)KC * D * 4;         // double
static constexpr size_t OFF_DONE  = OFF_NORM + 8;                        // u32
static constexpr size_t OFF_SCAL  = OFF_DONE + 4;                        // u32[3]: pos, open, olc
static constexpr size_t OFF_CNT   = OFF_SCAL + 12;                       // u32[512]
static constexpr size_t OFF_OPENL = OFF_CNT + (size_t)KC * 4;            // u16[512]
static constexpr size_t OFF_MCNT  = OFF_OPENL + (size_t)KC * 2;          // u32[512]
static constexpr size_t OFF_MEMB  = OFF_MCNT + (size_t)KC * 4;           // u32[512*256]
static constexpr size_t OFF_LBL   = OFF_MEMB + (size_t)KC * CAPC * 4;    // int32[NS]
static constexpr size_t OFF_SL    = ((OFF_LBL + (size_t)NS * 4 + 15) / 16) * 16; // u16[NS*32]

struct PermArg { uint32_t v[KC]; };

// ---------------- device helpers ----------------
__device__ inline unsigned long long sortkey(double d) {
  unsigned long long u = (unsigned long long)__double_as_longlong(d);
  return (u & 0x8000000000000000ull) ? ~u : (u | 0x8000000000000000ull);
}

__device__ inline double dot128(const float* __restrict__ x, const float* __restrict__ y) {
  double s0 = 0, s1 = 0, s2 = 0, s3 = 0;
#pragma unroll
  for (int k = 0; k < D; k += 4) {
    float4 a = *reinterpret_cast<const float4*>(x + k);
    float4 b = *reinterpret_cast<const float4*>(y + k);
    s0 = fma((double)a.x, (double)b.x, s0);
    s1 = fma((double)a.y, (double)b.y, s1);
    s2 = fma((double)a.z, (double)b.z, s2);
    s3 = fma((double)a.w, (double)b.w, s3);
  }
  return (s0 + s1) + (s2 + s3);
}

__device__ inline void bitonic64(unsigned long long& k, uint32_t& v, int lane) {
#pragma unroll
  for (int sz = 2; sz <= 64; sz <<= 1) {
#pragma unroll
    for (int st = sz >> 1; st > 0; st >>= 1) {
      unsigned long long ok = __shfl_xor(k, st);
      uint32_t ov = __shfl_xor(v, st);
      bool dirAsc = ((lane & sz) == 0);
      bool low = ((lane & st) == 0);
      bool oless = (ok < k) || (ok == k && ov < v);
      bool take = (dirAsc == low) ? oless : !oless;
      if (take) { k = ok; v = ov; }
    }
  }
}

// ---------------- init kernels ----------------
__global__ void k_init(uint32_t* done) {
  if (threadIdx.x == 0 && blockIdx.x == 0) *done = 0u;
}

__global__ void k_gather(PermArg p, const float* __restrict__ data, float* __restrict__ cb) {
  int c = blockIdx.x, t = threadIdx.x;
  cb[(size_t)c * D + t] = data[(size_t)p.v[c] * D + t];
}

// per-iteration prep: y2 (f64) and transposed f64 codebook
__global__ __launch_bounds__(64) void k_prep(const float* __restrict__ cb,
    double* __restrict__ yT, double* __restrict__ y2g, const uint32_t* __restrict__ done) {
  if (*done) return;
  const int c = blockIdx.x;
  const int lane = threadIdx.x;
  double v0 = (double)cb[(size_t)c * D + lane];
  double v1 = (double)cb[(size_t)c * D + 64 + lane];
  yT[(size_t)lane * KC + c] = v0;
  yT[(size_t)(lane + 64) * KC + c] = v1;
  double q = fma(v0, v0, v1 * v1);
  for (int d2 = 32; d2; d2 >>= 1) q += __shfl_xor(q, d2);
  if (lane == 0) y2g[c] = q;
}

// ---------------- fused f64 distance + exact top-32 shortlist ----------------
// block = 256 threads handles 16 rows; thread owns clusters (tid, tid+256) for all 16 rows.
__global__ __launch_bounds__(256) void k_dist(const float* __restrict__ data,
    const double* __restrict__ yT, const double* __restrict__ y2g,
    uint16_t* __restrict__ sl, const uint32_t* __restrict__ done) {
  if (*done) return;
  __shared__ double xs[16][D];
  __shared__ uint32_t hist[256];
  __shared__ unsigned long long candK[64];
  __shared__ uint32_t candI[64];
  __shared__ uint32_t candCnt;
  __shared__ double redMn[4], redMx[4];
  __shared__ double sKey[4];
  __shared__ int sId[4];
  __shared__ int cutSh;
  __shared__ uint32_t totSh;
  __shared__ int winSh;

  const int tid = threadIdx.x;
  const int lane = tid & 63;
  const int wv = tid >> 6;
  const int rowBase = blockIdx.x * 16;

  for (int idx = tid; idx < 16 * D; idx += 256) {
    int r = idx >> 7, k = idx & 127;
    xs[r][k] = (double)data[(size_t)(rowBase + r) * D + k];
  }
  __syncthreads();

  const int c0 = tid, c1 = tid + 256;
  double acc0[16], acc1[16];
#pragma unroll
  for (int r = 0; r < 16; ++r) { acc0[r] = 0.0; acc1[r] = 0.0; }

  for (int k = 0; k < D; ++k) {
    double yv0 = yT[(size_t)k * KC + c0];
    double yv1 = yT[(size_t)k * KC + c1];
#pragma unroll
    for (int r = 0; r < 16; ++r) {
      double xv = xs[r][k];
      acc0[r] = fma(xv, yv0, acc0[r]);
      acc1[r] = fma(xv, yv1, acc1[r]);
    }
  }
  {
    double y20 = y2g[c0], y21 = y2g[c1];
#pragma unroll
    for (int r = 0; r < 16; ++r) {
      acc0[r] = fma(-2.0, acc0[r], y20);   // S = y2 - 2 x.y
      acc1[r] = fma(-2.0, acc1[r], y21);
    }
  }

#pragma unroll
  for (int r = 0; r < 16; ++r) {
    const double v0 = acc0[r], v1 = acc1[r];
    // block min/max
    double mn = fmin(v0, v1), mx = fmax(v0, v1);
    for (int d2 = 32; d2; d2 >>= 1) {
      mn = fmin(mn, __shfl_xor(mn, d2));
      mx = fmax(mx, __shfl_xor(mx, d2));
    }
    if (lane == 0) { redMn[wv] = mn; redMx[wv] = mx; }
    __syncthreads();
    mn = fmin(fmin(redMn[0], redMn[1]), fmin(redMn[2], redMn[3]));
    mx = fmax(fmax(redMx[0], redMx[1]), fmax(redMx[2], redMx[3]));
    double rng = mx - mn;
    double inv = (rng > 0.0) ? (255.0 / rng) : 0.0;
    hist[tid] = 0;
    if (tid == 0) candCnt = 0;
    __syncthreads();
    int b0 = (int)((v0 - mn) * inv); b0 = b0 < 0 ? 0 : (b0 > 255 ? 255 : b0);
    int b1 = (int)((v1 - mn) * inv); b1 = b1 < 0 ? 0 : (b1 > 255 ? 255 : b1);
    atomicAdd(&hist[b0], 1u);
    atomicAdd(&hist[b1], 1u);
    __syncthreads();
    if (wv == 0) {
      uint32_t h0 = hist[lane * 4], h1 = hist[lane * 4 + 1], h2 = hist[lane * 4 + 2], h3 = hist[lane * 4 + 3];
      uint32_t ls = h0 + h1 + h2 + h3, x = ls;
      for (int d2 = 1; d2 < 64; d2 <<= 1) { uint32_t y = __shfl_up(x, d2); if (lane >= d2) x += y; }
      uint32_t e = x - ls;
      uint32_t cA = e + h0, cB = cA + h1, cC = cB + h2, cD = cC + h3;
      int mc = 999; uint32_t mt = 0;
      if (cA >= 32) { mc = lane * 4; mt = cA; }
      else if (cB >= 32) { mc = lane * 4 + 1; mt = cB; }
      else if (cC >= 32) { mc = lane * 4 + 2; mt = cC; }
      else if (cD >= 32) { mc = lane * 4 + 3; mt = cD; }
      for (int d2 = 32; d2; d2 >>= 1) {
        int oc = __shfl_xor(mc, d2); uint32_t ot = __shfl_xor(mt, d2);
        if (oc < mc) { mc = oc; mt = ot; }
      }
      if (lane == 0) { cutSh = mc; totSh = mt; }
    }
    __syncthreads();
    const int cut = cutSh;
    const uint32_t tot = totSh;
    if (tot <= 64u) {
      if (b0 <= cut) { uint32_t s2 = atomicAdd(&candCnt, 1u); candK[s2] = sortkey(v0); candI[s2] = (uint32_t)c0; }
      if (b1 <= cut) { uint32_t s2 = atomicAdd(&candCnt, 1u); candK[s2] = sortkey(v1); candI[s2] = (uint32_t)c1; }
      __syncthreads();
      if (wv == 0) {
        uint32_t nc = candCnt;
        unsigned long long kk = ~0ull; uint32_t id = 0xFFFFu;
        if ((uint32_t)lane < nc) { kk = candK[lane]; id = candI[lane]; }
        bitonic64(kk, id, lane);
        if (lane < TS) sl[(size_t)(rowBase + r) * TS + lane] = (uint16_t)id;
      }
      __syncthreads();
    } else {
      // exact slow path (rare): 32 rounds of block-wide argmin
      uint32_t tk = 0;
      for (int sel = 0; sel < 32; ++sel) {
        double bv = 1e300; int bc = 0x7FFFFFFF;
        if (!(tk & 1u)) { bv = v0; bc = c0; }
        if (!(tk & 2u) && (v1 < bv || (v1 == bv && c1 < bc))) { bv = v1; bc = c1; }
        for (int d2 = 32; d2; d2 >>= 1) {
          double ov = __shfl_xor(bv, d2); int oc = __shfl_xor(bc, d2);
          if (ov < bv || (ov == bv && oc < bc)) { bv = ov; bc = oc; }
        }
        if (lane == 0) { sKey[wv] = bv; sId[wv] = bc; }
        __syncthreads();
        if (tid == 0) {
          double fb = sKey[0]; int fc = sId[0];
          for (int w2 = 1; w2 < 4; ++w2) {
            if (sKey[w2] < fb || (sKey[w2] == fb && sId[w2] < fc)) { fb = sKey[w2]; fc = sId[w2]; }
          }
          winSh = fc;
          sl[(size_t)(rowBase + r) * TS + sel] = (uint16_t)fc;
        }
        __syncthreads();
        int wc = winSh;
        if (tid == (wc & 255)) tk |= (wc < 256) ? 1u : 2u;
        __syncthreads();
      }
    }
  }
}

// ---------------- sequential greedy (exact), single-wave event loop ----------------
__device__ inline int walkstep(const uint4 cc, const uint16_t* __restrict__ sl,
    uint32_t i, int& ptr, const uint32_t* cnt) {
  while (ptr < TS) {
    uint32_t c;
    if (ptr < 8) {
      uint32_t w = (ptr < 4) ? ((ptr < 2) ? cc.x : cc.y) : ((ptr < 6) ? cc.z : cc.w);
      c = (w >> ((ptr & 1) * 16)) & 0xFFFFu;
    } else {
      c = sl[(size_t)i * TS + ptr];
    }
    if (c < KC && cnt[c] < CAPC) return (int)c;
    ++ptr;
  }
  return -1;
}

__device__ inline void resolve_overflow(int& choice, uint32_t i, int lane,
    const uint32_t* cnt, const double* __restrict__ y2g,
    const float* __restrict__ cb, const float* __restrict__ data) {
  unsigned long long om = __ballot(choice < 0);
  while (om) {
    int L = __ffsll(om) - 1;
    om &= om - 1;
    uint32_t iL = __shfl(i, L);
    const float* x = data + (size_t)iL * D;
    double bv = 1e300; int bc = 0x7FFFFFFF;
    for (int j = 0; j < 8; ++j) {
      int c = lane + 64 * j;
      if (cnt[c] < CAPC) {
        double v = y2g[c] - 2.0 * dot128(x, cb + (size_t)c * D);
        if (v < bv || (v == bv && c < bc)) { bv = v; bc = c; }
      }
    }
    for (int d2 = 32; d2; d2 >>= 1) {
      double ov = __shfl_xor(bv, d2); int oc = __shfl_xor(bc, d2);
      if (ov < bv || (ov == bv && oc < bc)) { bv = ov; bc = oc; }
    }
    if (lane == L) choice = bc;
  }
}

__global__ __launch_bounds__(64) void k_ev(const float* __restrict__ data,
    const float* __restrict__ cb, const double* __restrict__ y2g,
    const uint16_t* __restrict__ sl, uint32_t* __restrict__ cntG,
    uint32_t* __restrict__ scal, uint16_t* __restrict__ openLG,
    int* __restrict__ labels, const uint32_t* __restrict__ done,
    int stopOpen, int initFlag) {
  if (*done) return;
  __shared__ uint32_t cnt[KC];
  __shared__ uint32_t hist[KC];
  __shared__ uint32_t reach[96];
  __shared__ uint32_t reachCnt;
  const int lane = threadIdx.x;

  uint32_t pos, openCnt;
  if (initFlag) {
    for (int c = lane; c < KC; c += 64) cnt[c] = 0;
    pos = 0; openCnt = KC;
  } else {
    for (int c = lane; c < KC; c += 64) cnt[c] = cntG[c];
    pos = scal[0]; openCnt = scal[1];
  }
  __syncthreads();

  // 5-deep shortlist prefix prefetch ring (never drained in the fast path)
  uint4 p0, p1, p2, p3, p4;
  {
    uint32_t s;
    s = pos + lane;        if (s >= NS) s = NS - 1; p0 = *reinterpret_cast<const uint4*>(sl + (size_t)s * TS);
    s = pos + 64 + lane;   if (s >= NS) s = NS - 1; p1 = *reinterpret_cast<const uint4*>(sl + (size_t)s * TS);
    s = pos + 128 + lane;  if (s >= NS) s = NS - 1; p2 = *reinterpret_cast<const uint4*>(sl + (size_t)s * TS);
    s = pos + 192 + lane;  if (s >= NS) s = NS - 1; p3 = *reinterpret_cast<const uint4*>(sl + (size_t)s * TS);
    s = pos + 256 + lane;  if (s >= NS) s = NS - 1; p4 = *reinterpret_cast<const uint4*>(sl + (size_t)s * TS);
  }

  while (pos < NS && openCnt > (uint32_t)stopOpen) {
    const uint32_t i = pos + lane;
    uint4 pN;
    {
      uint32_t s = pos + 320 + lane; if (s >= NS) s = NS - 1;
      pN = *reinterpret_cast<const uint4*>(sl + (size_t)s * TS);
    }

    // ---- fast choice: parallel prefix-count reads, pick first open ----
    uint32_t e0 = p0.x & 0xFFFFu, e1 = p0.x >> 16, e2 = p0.y & 0xFFFFu, e3 = p0.y >> 16,
             e4 = p0.z & 0xFFFFu, e5 = p0.z >> 16, e6 = p0.w & 0xFFFFu, e7 = p0.w >> 16;
    uint32_t q0 = cnt[e0 < KC ? e0 : 0], q1 = cnt[e1 < KC ? e1 : 0],
             q2 = cnt[e2 < KC ? e2 : 0], q3 = cnt[e3 < KC ? e3 : 0],
             q4 = cnt[e4 < KC ? e4 : 0], q5 = cnt[e5 < KC ? e5 : 0],
             q6 = cnt[e6 < KC ? e6 : 0], q7 = cnt[e7 < KC ? e7 : 0];
    int choice = -1, ptr = TS;
    if (e7 < KC && q7 < CAPC) { choice = (int)e7; ptr = 7; }
    if (e6 < KC && q6 < CAPC) { choice = (int)e6; ptr = 6; }
    if (e5 < KC && q5 < CAPC) { choice = (int)e5; ptr = 5; }
    if (e4 < KC && q4 < CAPC) { choice = (int)e4; ptr = 4; }
    if (e3 < KC && q3 < CAPC) { choice = (int)e3; ptr = 3; }
    if (e2 < KC && q2 < CAPC) { choice = (int)e2; ptr = 2; }
    if (e1 < KC && q1 < CAPC) { choice = (int)e1; ptr = 1; }
    if (e0 < KC && q0 < CAPC) { choice = (int)e0; ptr = 0; }
    if (__ballot(choice < 0)) {           // deep walk beyond the register prefix (L1-resident line)
      if (choice < 0) { ptr = 8; choice = walkstep(p0, sl, i, ptr, cnt); }
    }
    resolve_overflow(choice, i, lane, cnt, y2g, cb, data);

    // ---- optimistic commit: one ds_add_rtn; overflow <=> any(old >= CAPC) ----
    uint32_t old = atomicAdd(&cnt[choice], 1u);
    unsigned long long ovf = __ballot(old >= CAPC);
    if (ovf == 0ull) {
      // no cluster exceeded capacity: all 64 choices match the sequential scan
      labels[i] = choice;
      unsigned long long fills = __ballot(old == CAPC - 1);
      openCnt -= (uint32_t)__popcll(fills);
    } else {
      // roll back and run the exact validation machinery (rare)
      atomicSub(&cnt[choice], 1u);
      __syncthreads();
      bool exempt = false;
      for (;;) {
        for (int c = lane; c < KC; c += 64) hist[c] = 0;
        if (lane == 0) reachCnt = 0;
        __syncthreads();
        if (!exempt) atomicAdd(&hist[choice], 1u);
        __syncthreads();
        for (int c = lane; c < KC; c += 64) {
          uint32_t cc = cnt[c];
          if (cc < CAPC && cc + hist[c] >= CAPC) {
            uint32_t s2 = atomicAdd(&reachCnt, 1u);
            if (s2 < 96) reach[s2] = c;
          }
        }
        __syncthreads();
        uint32_t nr = reachCnt; if (nr > 96) nr = 96;
        if (nr == 0) break;
        // pass 1: earliest invalid lane L*
        int Lstar = 64;
        for (uint32_t t = 0; t < nr; ++t) {
          uint32_t c = reach[t];
          uint32_t rem = CAPC - cnt[c];
          unsigned long long m = __ballot((!exempt) && choice == (int)c);
          if ((uint32_t)__popcll(m) > rem) {
            unsigned long long mm = m;
            for (uint32_t q = 0; q < rem; ++q) mm &= mm - 1;
            int fi = __ffsll(mm) - 1;
            if (fi < Lstar) Lstar = fi;
          }
        }
        if (Lstar == 64) break;  // only exact fills; commit via atomics below
        // pass 2: fill every cluster whose fill lane precedes L*
        bool inval = false;
        for (uint32_t t = 0; t < nr; ++t) {
          uint32_t c = reach[t];
          uint32_t cc = cnt[c];
          if (cc >= CAPC) continue;
          uint32_t rem = CAPC - cc;
          unsigned long long m = __ballot((!exempt) && choice == (int)c);
          uint32_t pc = (uint32_t)__popcll(m);
          if (pc >= rem) {
            unsigned long long mm = m;
            for (uint32_t q = 0; q + 1 < rem; ++q) mm &= mm - 1;
            int fl = __ffsll(mm) - 1;
            if (fl < Lstar) {
              __syncthreads();
              if (lane == 0) cnt[c] = CAPC;
              openCnt--;   // wave-uniform
              __syncthreads();
              if ((!exempt) && choice == (int)c) {
                uint32_t rk = (uint32_t)__popcll(m & ((1ull << lane) - 1ull));
                if (rk < rem) exempt = true; else inval = true;
              }
            }
          }
        }
        __syncthreads();
        if (inval) {
          if (ptr < TS) { ++ptr; choice = walkstep(p0, sl, i, ptr, cnt); }
          else choice = -1;
        }
        resolve_overflow(choice, i, lane, cnt, y2g, cb, data);
        __syncthreads();
      }
      uint32_t oldc = 0;
      if (!exempt) oldc = atomicAdd(&cnt[choice], 1u);
      labels[i] = choice;
      unsigned long long fills = __ballot((!exempt) && oldc == CAPC - 1);
      openCnt -= (uint32_t)__popcll(fills);
      __syncthreads();
    }

    pos += 64;
    p0 = p1; p1 = p2; p2 = p3; p3 = p4; p4 = pN;
  }

  __syncthreads();
  for (int c = lane; c < KC; c += 64) cntG[c] = cnt[c];
  uint32_t base = 0;
  for (int j = 0; j < 8; ++j) {
    int c = lane + 64 * j;
    bool op = cnt[c] < CAPC;
    unsigned long long m = __ballot(op);
    uint32_t rk = (uint32_t)__popcll(m & ((1ull << lane) - 1ull));
    if (op) openLG[base + rk] = (uint16_t)c;
    base += (uint32_t)__popcll(m);
  }
  if (lane == 0) { scal[0] = pos; scal[1] = openCnt; scal[2] = base; }
}

// rebuild shortlists for remaining samples over the (<=64) open clusters
__global__ __launch_bounds__(256) void k_rebuild(const float* __restrict__ data,
    const float* __restrict__ cb, const double* __restrict__ y2g,
    uint16_t* __restrict__ sl, const uint32_t* __restrict__ scal,
    const uint16_t* __restrict__ openLG, const uint32_t* __restrict__ done) {
  if (*done) return;
  uint32_t pos = scal[0];
  if (pos >= NS) return;
  uint32_t oc = scal[2]; if (oc > 64) oc = 64;
  const int lane = threadIdx.x & 63;
  const uint32_t wid = (blockIdx.x * blockDim.x + threadIdx.x) >> 6;
  const uint32_t nw = (gridDim.x * blockDim.x) >> 6;
  int c = -1; double y2v = 0.0; const float* yrow = cb;
  if ((uint32_t)lane < oc) { c = openLG[lane]; y2v = y2g[c]; yrow = cb + (size_t)c * D; }
  for (uint32_t s = pos + wid; s < NS; s += nw) {
    unsigned long long kk = ~0ull; uint32_t id = 0xFFFFu;
    if (c >= 0) {
      double v = y2v - 2.0 * dot128(data + (size_t)s * D, yrow);
      kk = sortkey(v); id = (uint32_t)c;
    }
    bitonic64(kk, id, lane);
    if (lane < TS) sl[(size_t)s * TS + lane] = (uint16_t)id;
  }
}

// ---------------- codebook update ----------------
__global__ void k_zero(uint32_t* mcnt, double* norm) {
  int i = blockIdx.x * blockDim.x + threadIdx.x;
  if (i < KC) mcnt[i] = 0u;
  if (i == 0) *norm = 0.0;
}

__global__ void k_scatter(const int* __restrict__ labels, uint32_t* __restrict__ mcnt,
    uint32_t* __restrict__ memb, const uint32_t* __restrict__ done) {
  if (*done) return;
  uint32_t i = blockIdx.x * blockDim.x + threadIdx.x;
  int c = labels[i];
  if ((unsigned)c < KC) {
    uint32_t s = atomicAdd(&mcnt[c], 1u);
    if (s < CAPC) memb[(size_t)c * CAPC + s] = i;
  }
}

__global__ __launch_bounds__(128) void k_update(const float* __restrict__ data,
    const uint32_t* __restrict__ memb, float* __restrict__ cb,
    double* __restrict__ norm, const uint32_t* __restrict__ done) {
  if (*done) return;
  const int c = blockIdx.x, t = threadIdx.x;
  __shared__ uint32_t mem[CAPC];
  __shared__ double qq[2];
  mem[t] = memb[(size_t)c * CAPC + t] & (NS - 1);
  mem[t + 128] = memb[(size_t)c * CAPC + 128 + t] & (NS - 1);
  __syncthreads();
  double a = 0.0;
  for (int m = 0; m < CAPC; ++m) a += (double)data[(size_t)mem[m] * D + t];
  float nv = (float)(a * (1.0 / 256.0));
  double df = (double)nv - (double)cb[(size_t)c * D + t];
  cb[(size_t)c * D + t] = nv;
  double q = df * df;
  for (int d2 = 32; d2; d2 >>= 1) q += __shfl_xor(q, d2);
  if ((t & 63) == 0) qq[t >> 6] = q;
  __syncthreads();
  if (t == 0) atomicAdd(norm, qq[0] + qq[1]);
}

__global__ void k_conv(const double* __restrict__ norm, uint32_t* __restrict__ done) {
  if (threadIdx.x == 0 && blockIdx.x == 0) {
    if (*norm < 1e-8) *done = 1u;   // norm < 1e-4  <=>  norm^2 < 1e-8
  }
}

__global__ void k_out(const float* __restrict__ cb, float* __restrict__ o) {
  int i = blockIdx.x * blockDim.x + threadIdx.x;
  o[i] = cb[i];
}

// labels are int32 internally; harness reads the whole d_out as float32 -> emit float values
__global__ void k_outL(const int* __restrict__ lbl, float* __restrict__ o) {
  int i = blockIdx.x * blockDim.x + threadIdx.x;
  o[i] = (float)lbl[i];
}

// ---------------- host: JAX threefry permutation (input-independent) ----------------
static void tf2x32(uint32_t k0, uint32_t k1, uint32_t x0, uint32_t x1, uint32_t& o0, uint32_t& o1) {
  uint32_t ks2 = k0 ^ k1 ^ 0x1BD11BDAu;
  x0 += k0; x1 += k1;
  auto R = [&](int r) { x0 += x1; x1 = (x1 << r) | (x1 >> (32 - r)); x1 ^= x0; };
  R(13); R(15); R(26); R(6);   x0 += k1;  x1 += ks2 + 1u;
  R(17); R(29); R(16); R(24);  x0 += ks2; x1 += k0 + 2u;
  R(13); R(15); R(26); R(6);   x0 += k0;  x1 += k1 + 3u;
  R(17); R(29); R(16); R(24);  x0 += k1;  x1 += ks2 + 4u;
  R(13); R(15); R(26); R(6);   x0 += ks2; x1 += k0 + 5u;
  o0 = x0; o1 = x1;
}

static void host_sort_kv(std::vector<uint32_t>& k, std::vector<uint32_t>& v) {
  const size_t n = k.size();
  std::vector<uint32_t> k2(n), v2(n);
  for (int sh = 0; sh < 32; sh += 8) {
    uint32_t cnt2[257];
    memset(cnt2, 0, sizeof cnt2);
    for (size_t i = 0; i < n; ++i) cnt2[((k[i] >> sh) & 255u) + 1]++;
    for (int b = 0; b < 256; ++b) cnt2[b + 1] += cnt2[b];
    for (size_t i = 0; i < n; ++i) {
      uint32_t b = (k[i] >> sh) & 255u;
      uint32_t d = cnt2[b]++;
      k2[d] = k[i]; v2[d] = v[i];
    }
    k.swap(k2); v.swap(v2);
  }
}

static void compute_perm(uint32_t* out) {
  const uint32_t n = NS;
  std::vector<uint32_t> vals(n), keys(n);
  for (uint32_t i = 0; i < n; ++i) vals[i] = i;
  uint32_t k0 = 0u, k1 = 42u;  // jax.random.key(42) -> [0, 42]
  for (int round = 0; round < 2; ++round) {   // num_rounds = ceil(3*ln(131072)/ln(2^32-1)) = 2
    uint32_t nk0, nk1, sk0, sk1;
#if RNG_PARTITIONABLE
    tf2x32(k0, k1, 0u, 0u, nk0, nk1);  // split-foldlike: keys[i] = TF(key,(0,i))
    tf2x32(k0, k1, 0u, 1u, sk0, sk1);
    for (uint32_t i = 0; i < n; ++i) {
      uint32_t b1, b2;
      tf2x32(sk0, sk1, 0u, i, b1, b2);
      keys[i] = b1 ^ b2;                // 32-bit bits = bits1 ^ bits2
    }
#else
    {
      uint32_t a0, b0, a1, b1v;
      tf2x32(k0, k1, 0u, 2u, a0, b0);  // original split: counts iota(4), pairs (0,2),(1,3)
      tf2x32(k0, k1, 1u, 3u, a1, b1v);
      nk0 = a0; nk1 = a1; sk0 = b0; sk1 = b1v;
    }
    {
      const uint32_t h = n / 2;
      for (uint32_t i = 0; i < h; ++i) {
        uint32_t o0, o1;
        tf2x32(sk0, sk1, i, i + h, o0, o1);
        keys[i] = o0; keys[i + h] = o1;
      }
    }
#endif
    host_sort_kv(keys, vals);  // stable ascending == lax.sort_key_val
    k0 = nk0; k1 = nk1;
  }
  memcpy(out, vals.data(), KC * sizeof(uint32_t));
}

// ---------------- launcher ----------------
extern "C" void kernel_launch(void* const* d_in, const int* in_sizes, int n_in,
                              void* d_out, int out_size, void* d_ws, size_t ws_size,
                              hipStream_t stream) {
  const float* data = (const float*)d_in[0];
  float* outCB = (float*)d_out;
  float* outLB = (float*)d_out + (size_t)KC * D;

  char* w = (char*)d_ws;
  double* yT = (double*)(w + OFF_YT);
  double* y2 = (double*)(w + OFF_Y2);
  float* cb = (float*)(w + OFF_CB);
  double* norm = (double*)(w + OFF_NORM);
  uint32_t* done = (uint32_t*)(w + OFF_DONE);
  uint32_t* scal = (uint32_t*)(w + OFF_SCAL);
  uint32_t* cnt = (uint32_t*)(w + OFF_CNT);
  uint16_t* openL = (uint16_t*)(w + OFF_OPENL);
  uint32_t* mcnt = (uint32_t*)(w + OFF_MCNT);
  uint32_t* memb = (uint32_t*)(w + OFF_MEMB);
  int* lbl = (int*)(w + OFF_LBL);
  uint16_t* sl = (uint16_t*)(w + OFF_SL);

  PermArg pa;
  compute_perm(pa.v);  // deterministic host work each call (capture-time only)

  k_init<<<1, 64, 0, stream>>>(done);
  k_gather<<<KC, D, 0, stream>>>(pa, data, cb);

  for (int it = 0; it < 3; ++it) {
    k_prep<<<KC, 64, 0, stream>>>(cb, yT, y2, done);
    k_dist<<<NS / 16, 256, 0, stream>>>(data, yT, y2, sl, done);
    k_ev<<<1, 64, 0, stream>>>(data, cb, y2, sl, cnt, scal, openL, lbl, done, 64, 1);
    k_rebuild<<<256, 256, 0, stream>>>(data, cb, y2, sl, scal, openL, done);
    k_ev<<<1, 64, 0, stream>>>(data, cb, y2, sl, cnt, scal, openL, lbl, done, 32, 0);
    k_rebuild<<<256, 256, 0, stream>>>(data, cb, y2, sl, scal, openL, done);
    k_ev<<<1, 64, 0, stream>>>(data, cb, y2, sl, cnt, scal, openL, lbl, done, 0, 0);
    k_zero<<<2, 256, 0, stream>>>(mcnt, norm);
    k_scatter<<<NS / 256, 256, 0, stream>>>(lbl, mcnt, memb, done);
    k_update<<<KC, 128, 0, stream>>>(data, memb, cb, norm, done);
    k_conv<<<1, 64, 0, stream>>>(norm, done);
  }
  k_out<<<KC * D / 256, 256, 0, stream>>>(cb, outCB);
  k_outL<<<NS / 256, 256, 0, stream>>>(lbl, outLB);
}